// Round 15
// baseline (20885.991 us; speedup 1.0000x reference)
//
#include <hip/hip_runtime.h>
#include <cmath>

#define LEAK 0.95f
#define ILEAK 0.05f

typedef float f4 __attribute__((ext_vector_type(4)));
typedef unsigned long long ull;

// ---------------- Phase 1: u = x @ W_in^T (fp32 tiled GEMM) ----------------
__global__ __launch_bounds__(256) void resv_gemm_uin(
    const float* __restrict__ A, const float* __restrict__ Bm,
    float* __restrict__ C, int M, int N, int K)
{
    __shared__ float As[16][68];
    __shared__ float Bs[16][68];
    const int tid = threadIdx.x;
    const int m0 = blockIdx.y * 64;
    const int n0 = blockIdx.x * 64;
    const int lm = tid >> 2;
    const int lk = (tid & 3) * 4;
    const int ty = tid >> 4;
    const int tx = tid & 15;

    float acc[4][4];
#pragma unroll
    for (int i = 0; i < 4; ++i)
#pragma unroll
        for (int j = 0; j < 4; ++j) acc[i][j] = 0.f;

    const float* Aptr = A + (size_t)(m0 + lm) * K + lk;
    const float* Bptr = Bm + (size_t)(n0 + lm) * K + lk;

    for (int k0 = 0; k0 < K; k0 += 16) {
        float4 av = *(const float4*)(Aptr + k0);
        float4 bv = *(const float4*)(Bptr + k0);
        __syncthreads();
        As[lk + 0][lm] = av.x; As[lk + 1][lm] = av.y;
        As[lk + 2][lm] = av.z; As[lk + 3][lm] = av.w;
        Bs[lk + 0][lm] = bv.x; Bs[lk + 1][lm] = bv.y;
        Bs[lk + 2][lm] = bv.z; Bs[lk + 3][lm] = bv.w;
        __syncthreads();
#pragma unroll
        for (int kk = 0; kk < 16; ++kk) {
            float4 a = *(const float4*)(&As[kk][ty * 4]);
            float4 b = *(const float4*)(&Bs[kk][tx * 4]);
            acc[0][0] += a.x * b.x; acc[0][1] += a.x * b.y; acc[0][2] += a.x * b.z; acc[0][3] += a.x * b.w;
            acc[1][0] += a.y * b.x; acc[1][1] += a.y * b.y; acc[1][2] += a.y * b.z; acc[1][3] += a.y * b.w;
            acc[2][0] += a.z * b.x; acc[2][1] += a.z * b.y; acc[2][2] += a.z * b.z; acc[2][3] += a.z * b.w;
            acc[3][0] += a.w * b.x; acc[3][1] += a.w * b.y; acc[3][2] += a.w * b.z; acc[3][3] += a.w * b.w;
        }
    }
    float* Cp = C + (size_t)(m0 + ty * 4) * N + n0 + tx * 4;
#pragma unroll
    for (int i = 0; i < 4; ++i) {
        float4 v = make_float4(acc[i][0], acc[i][1], acc[i][2], acc[i][3]);
        *(float4*)(Cp + (size_t)i * N) = v;
    }
}

// ---------------- Phase 2: reservoir recurrence, data-tagged sync ---------
// r12 sync skeleton byte-for-byte (sentinel tag-poll with v[16], 3 barriers,
// [slot][g][h][b] pairs, full-line publish h0*4+tid). Compute: 2-ROW mapping
// (the spill-safe point between r12's 1-row and r14's spilled 4-row):
//  - lane = (row-pair rp=l>>2 -> rows h0+2rp,+1; k-lane li=l&3 -> 64
//    contiguous k at w*256+li*64). One ds_read_b128 = 1 k x 4 batches feeds
//    2 rows (8 FMA) -> 64 reads/lane = 256 LDS instrs/CU/step (2x fewer).
//  - W = 2 rows x 16 contiguous f4 loads. Registers: 128 W + 8 acc + 32
//    poll ~= 195 (r10/r11/r13/r14 spilled at 16-float acc; r7/r12 = 188 ok).
//  - prevI padded 1 f4 per 32 h (fk=h+(h>>5)): the 4 li-lanes land at dword
//    offsets {0,8,16,24} mod 32 -> 4 disjoint 16B slots, 16-group broadcast,
//    conflict-free. Staging float idx: n + ((n>>7)<<2), n = c*256+tid.
//  - reduce over 4 k-lanes: 2 shuffle rounds x 8 floats.
__global__ __launch_bounds__(256, 1) void resv_recur(
    const float* __restrict__ Wres,   // [1024][1024]
    float* __restrict__ out,          // [32][2048][1024] (pre-filled with u)
    ull* __restrict__ pairs)          // ws: [2 slots][8 g][1024 h][4 b] pairs
{
    constexpr int H = 1024, S = 2048;
    extern __shared__ float sm[];
    float* prevI = sm;                 // [1056 f4] padded [h][b] (16.9 KB)
    float* uL    = sm + 4224;          // [2][2048] double-buffered u (16 KB)
    float* red   = sm + 4224 + 4096;   // [4 q][32 row][4 b] floats (2 KB)

    const int tid = threadIdx.x;
    const int g  = blockIdx.x & 7;
    const int r  = blockIdx.x >> 3;
    const int h0 = r * 32;
    const int b0 = g * 4;

    const int w  = tid >> 6;           // wave = k-quarter
    const int l  = tid & 63;
    const int rp = l >> 2;             // row-pair 0..15 (rows h0+2rp, +1)
    const int li = l & 3;              // k-lane: contiguous k w*256+li*64..+63

    // ---- one-time: W[h0+2rp+rr][w*256+li*64 ..+63] as 2x16 f4 vectors ----
    f4 Wreg[2][16];
#pragma unroll
    for (int rr = 0; rr < 2; ++rr) {
        const f4* wsrc = (const f4*)(Wres + (size_t)(h0 + 2 * rp + rr) * H
                                     + (w * 256 + li * 64));
#pragma unroll
        for (int j4 = 0; j4 < 16; ++j4) Wreg[rr][j4] = wsrc[j4];
    }

    const int fb  = tid & 3;           // finish: batch
    const int frw = tid >> 2;          // finish: row (tid<128 -> frw<32)
    float pv = 0.f;                    // finish thread's own previous value

    for (int t = 0; t < S; ++t) {
        // ---- stage u[t..t+15] into double buffer (own region, plain) ----
        if ((t & 15) == 0) {
            float* uB = uL + ((t >> 4) & 1) * 2048;
            for (int c = tid; c < 512; c += 256) {
                int rw4 = c & 7, b = (c >> 3) & 3, tt = c >> 5;
                const float4* src =
                    (const float4*)(out + ((size_t)(b0 + b) * S + (t + tt)) * H + h0);
                ((float4*)uB)[(tt * 4 + b) * 8 + rw4] = src[rw4];
            }
        }
        // ---- poll: sentinel wait (4/lane), then bulk + verify (r12) ----
        {
            const ull* src = pairs + ((size_t)((t & 1) * 8 + g)) * 4096;
            const unsigned tgt = (unsigned)t;
            ull v[16];
            // 1) sentinel wait: c = 0,5,10,15
            for (;;) {
                ull s0 = __hip_atomic_load(src + 0 * 256 + tid, __ATOMIC_RELAXED,
                                           __HIP_MEMORY_SCOPE_AGENT);
                ull s1 = __hip_atomic_load(src + 5 * 256 + tid, __ATOMIC_RELAXED,
                                           __HIP_MEMORY_SCOPE_AGENT);
                ull s2 = __hip_atomic_load(src + 10 * 256 + tid, __ATOMIC_RELAXED,
                                           __HIP_MEMORY_SCOPE_AGENT);
                ull s3 = __hip_atomic_load(src + 15 * 256 + tid, __ATOMIC_RELAXED,
                                           __HIP_MEMORY_SCOPE_AGENT);
                int ok = ((unsigned)(s0 >> 32) == tgt) & ((unsigned)(s1 >> 32) == tgt)
                       & ((unsigned)(s2 >> 32) == tgt) & ((unsigned)(s3 >> 32) == tgt);
                if (__all(ok)) { v[0] = s0; v[5] = s1; v[10] = s2; v[15] = s3; break; }
            }
            // 2) bulk-load remaining 12, verify; rare stale -> full retry
            for (;;) {
                int ok = 1;
#pragma unroll
                for (int c = 0; c < 16; ++c) {
                    if (c == 0 || c == 5 || c == 10 || c == 15) continue;
                    v[c] = __hip_atomic_load(src + c * 256 + tid, __ATOMIC_RELAXED,
                                             __HIP_MEMORY_SCOPE_AGENT);
                    ok &= ((unsigned)(v[c] >> 32) == tgt);
                }
                if (__all(ok)) break;
            }
            // store to padded LDS: float idx = n + ((n>>7)<<2), n = c*256+tid
#pragma unroll
            for (int c = 0; c < 16; ++c) {
                int n = c * 256 + tid;
                prevI[n + ((n >> 7) << 2)] = __uint_as_float((unsigned)v[c]);
            }
        }
        __syncthreads();

        // ---- compute: 2 rows x 4 batches/lane; 64 b128 reads, 8 FMA each --
        f4 acc0 = (f4)(0.f), acc1 = (f4)(0.f);
        const f4* P = (const f4*)prevI;
        const int fbase = w * 264 + li * 66;   // padded f4 base (k -> k+(k>>5))
#pragma unroll
        for (int jj = 0; jj < 32; ++jj) {
            f4 pa = P[fbase + jj];             // k = kbase+jj
            f4 pb = P[fbase + 33 + jj];        // k = kbase+32+jj (pad-aware)
            acc0 += Wreg[0][jj >> 2][jj & 3] * pa;
            acc1 += Wreg[1][jj >> 2][jj & 3] * pa;
            acc0 += Wreg[0][8 + (jj >> 2)][jj & 3] * pb;
            acc1 += Wreg[1][8 + (jj >> 2)][jj & 3] * pb;
        }
        // reduce over the 4 k-lanes (xor 1,2)
#pragma unroll
        for (int m = 1; m <= 2; m <<= 1) {
            acc0.x += __shfl_xor(acc0.x, m, 64); acc0.y += __shfl_xor(acc0.y, m, 64);
            acc0.z += __shfl_xor(acc0.z, m, 64); acc0.w += __shfl_xor(acc0.w, m, 64);
            acc1.x += __shfl_xor(acc1.x, m, 64); acc1.y += __shfl_xor(acc1.y, m, 64);
            acc1.z += __shfl_xor(acc1.z, m, 64); acc1.w += __shfl_xor(acc1.w, m, 64);
        }
        if (li == 0) {
            f4* rd = (f4*)red + (w * 32 + 2 * rp);
            rd[0] = acc0; rd[1] = acc1;
        }
        __syncthreads();

        // ---- finish (tid<128): publish tagged pair, FULL-LINE order ----
        if (tid < 128) {
            float sum = red[(0 * 32 + frw) * 4 + fb] + red[(1 * 32 + frw) * 4 + fb]
                      + red[(2 * 32 + frw) * 4 + fb] + red[(3 * 32 + frw) * 4 + fb];
            float uv = uL[((t >> 4) & 1) * 2048 + (((t & 15) * 4 + fb) << 5) + frw];
            float ns = LEAK * tanhf(uv + sum) + ILEAK * pv;
            pv = ns;
            ull pk = ((ull)(unsigned)(t + 1) << 32) | (ull)__float_as_uint(ns);
            // pair idx (h0+frw)*4+fb == h0*4+tid: 128 consecutive ull
            __hip_atomic_store(
                pairs + ((size_t)(((t + 1) & 1) * 8 + g)) * 4096 + h0 * 4 + tid,
                pk, __ATOMIC_RELAXED, __HIP_MEMORY_SCOPE_AGENT);
            out[((size_t)(b0 + fb) * S + t) * H + h0 + frw] = ns;
        }
        __syncthreads();
    }
}

extern "C" void kernel_launch(void* const* d_in, const int* in_sizes, int n_in,
                              void* d_out, int out_size, void* d_ws, size_t ws_size,
                              hipStream_t stream)
{
    const float* x    = (const float*)d_in[0];   // [32][2048][512]
    const float* Win  = (const float*)d_in[1];   // [1024][512]
    const float* Wres = (const float*)d_in[2];   // [1024][1024]
    float* out = (float*)d_out;                  // [32][2048][1024]

    ull* pairs = (ull*)d_ws;                     // 2*8*4096*8 = 524288 B

    // zero pairs every launch: (tag 0, 0.0f) == step-0 initial state
    hipMemsetAsync(d_ws, 0, 524288, stream);

    // phase 1: u = x @ W_in^T into d_out
    dim3 gemm_grid(1024 / 64, 65536 / 64);
    resv_gemm_uin<<<gemm_grid, 256, 0, stream>>>(x, Win, out, 65536, 1024, 512);

    // phase 2: recurrence. 96KB dynamic LDS pins exactly 1 wg/CU
    // (co-residency of all 256 wgs proven rounds 1-14).
    constexpr int kLds = 96 * 1024;
    hipFuncSetAttribute((const void*)resv_recur,
                        hipFuncAttributeMaxDynamicSharedMemorySize, kLds);
    resv_recur<<<dim3(256), dim3(256), kLds, stream>>>(Wres, out, pairs);
}

// Round 16
// 5204.964 us; speedup vs baseline: 4.0127x; 4.0127x over previous
//
#include <hip/hip_runtime.h>
#include <cmath>

#define LEAK 0.95f
#define ILEAK 0.05f

typedef float f4 __attribute__((ext_vector_type(4)));
typedef short s8 __attribute__((ext_vector_type(8)));   // 8 bf16 = 4 VGPRs
typedef unsigned long long ull;

// ---------------- Phase 1: u = x @ W_in^T (fp32 tiled GEMM) ----------------
__global__ __launch_bounds__(256) void resv_gemm_uin(
    const float* __restrict__ A, const float* __restrict__ Bm,
    float* __restrict__ C, int M, int N, int K)
{
    __shared__ float As[16][68];
    __shared__ float Bs[16][68];
    const int tid = threadIdx.x;
    const int m0 = blockIdx.y * 64;
    const int n0 = blockIdx.x * 64;
    const int lm = tid >> 2;
    const int lk = (tid & 3) * 4;
    const int ty = tid >> 4;
    const int tx = tid & 15;

    float acc[4][4];
#pragma unroll
    for (int i = 0; i < 4; ++i)
#pragma unroll
        for (int j = 0; j < 4; ++j) acc[i][j] = 0.f;

    const float* Aptr = A + (size_t)(m0 + lm) * K + lk;
    const float* Bptr = Bm + (size_t)(n0 + lm) * K + lk;

    for (int k0 = 0; k0 < K; k0 += 16) {
        float4 av = *(const float4*)(Aptr + k0);
        float4 bv = *(const float4*)(Bptr + k0);
        __syncthreads();
        As[lk + 0][lm] = av.x; As[lk + 1][lm] = av.y;
        As[lk + 2][lm] = av.z; As[lk + 3][lm] = av.w;
        Bs[lk + 0][lm] = bv.x; Bs[lk + 1][lm] = bv.y;
        Bs[lk + 2][lm] = bv.z; Bs[lk + 3][lm] = bv.w;
        __syncthreads();
#pragma unroll
        for (int kk = 0; kk < 16; ++kk) {
            float4 a = *(const float4*)(&As[kk][ty * 4]);
            float4 b = *(const float4*)(&Bs[kk][tx * 4]);
            acc[0][0] += a.x * b.x; acc[0][1] += a.x * b.y; acc[0][2] += a.x * b.z; acc[0][3] += a.x * b.w;
            acc[1][0] += a.y * b.x; acc[1][1] += a.y * b.y; acc[1][2] += a.y * b.z; acc[1][3] += a.y * b.w;
            acc[2][0] += a.z * b.x; acc[2][1] += a.z * b.y; acc[2][2] += a.z * b.z; acc[2][3] += a.z * b.w;
            acc[3][0] += a.w * b.x; acc[3][1] += a.w * b.y; acc[3][2] += a.w * b.z; acc[3][3] += a.w * b.w;
        }
    }
    float* Cp = C + (size_t)(m0 + ty * 4) * N + n0 + tx * 4;
#pragma unroll
    for (int i = 0; i < 4; ++i) {
        float4 v = make_float4(acc[i][0], acc[i][1], acc[i][2], acc[i][3]);
        *(float4*)(Cp + (size_t)i * N) = v;
    }
}

__device__ __forceinline__ ushort f32_to_bf16_rne(float x) {
    unsigned u = __float_as_uint(x);
    return (ushort)((u + 0x7FFFu + ((u >> 16) & 1u)) >> 16);
}

// ---------------- Phase 2: reservoir recurrence, MFMA compute -------------
// r12 sync skeleton byte-for-byte (sentinel tag-poll v[16], 3 barriers,
// [slot][g][h][b] pairs, full-line publish h0*4+tid). Compute replaced by
// bf16 MFMA (16x16x32): per wg the matvec is [32 rows x 1024 k]x[1024 k x 4b]
// -> per wave (k-quarter): 2 M-tiles x 8 K-tiles = 16 MFMA. W held as 16
// pre-packed A-fragments (64 VGPR, HALF of the spilled designs' 128-float
// Wreg). B cols 4..15 are garbage duplicates (never consumed). LAYOUT RISK
// CONTAINED: A- and B-frags use the SAME slot->k map (contiguous 8 per
// lane-group), so any mismatch vs the true HW map is a common k-permutation
// that cancels in the dot product. C/D map col=l&15,row=4*(l>>4)+j (m89).
// bf16 error budget: ~2e-3/step pre-tanh, contractive recurrence -> ~7e-3
// steady-state, threshold 2e-2.
__global__ __launch_bounds__(256, 1) void resv_recur(
    const float* __restrict__ Wres,   // [1024][1024]
    float* __restrict__ out,          // [32][2048][1024] (pre-filled with u)
    ull* __restrict__ pairs)          // ws: [2 slots][8 g][1024 h][4 b] pairs
{
    constexpr int H = 1024, S = 2048;
    extern __shared__ char smraw[];
    ushort* Bb  = (ushort*)smraw;               // [4 b][1040] bf16 (8320 B)
    float*  uL  = (float*)(smraw + 8448);       // [2][2048] u dbuf (16 KB)
    float*  red = (float*)(smraw + 8448 + 16384); // [4 q][32 row][4 b] (2 KB)

    const int tid = threadIdx.x;
    const int g  = blockIdx.x & 7;
    const int r  = blockIdx.x >> 3;
    const int h0 = r * 32;
    const int b0 = g * 4;

    const int w  = tid >> 6;           // wave = k-quarter (k in [w*256, +256))
    const int l  = tid & 63;
    const int lg = l >> 4;             // lane-group 0..3
    const int lc = l & 15;             // A-row / B-col / C-col index

    // ---- one-time: W A-fragments, 2 M-tiles x 8 K-tiles, slot k-map
    //      k = w*256 + kt*32 + lg*8 + j (contiguous 8) ----
    s8 Afrag[16];
#pragma unroll
    for (int m = 0; m < 2; ++m)
#pragma unroll
        for (int kt = 0; kt < 8; ++kt) {
            const float* wp = Wres + (size_t)(h0 + m * 16 + lc) * H
                            + (w * 256 + kt * 32 + lg * 8);
            s8 a;
#pragma unroll
            for (int j = 0; j < 8; ++j) a[j] = (short)f32_to_bf16_rne(wp[j]);
            Afrag[m * 8 + kt] = a;
        }

    const int fb  = tid & 3;           // finish: batch
    const int frw = tid >> 2;          // finish: row (tid<128 -> frw<32)
    float pv = 0.f;                    // finish thread's own previous value

    const ushort* bbase = Bb + (size_t)(lc & 3) * 1040 + w * 256 + lg * 8;

    for (int t = 0; t < S; ++t) {
        // ---- stage u[t..t+15] into double buffer (own region, plain) ----
        if ((t & 15) == 0) {
            float* uB = uL + ((t >> 4) & 1) * 2048;
            for (int c = tid; c < 512; c += 256) {
                int rw4 = c & 7, b = (c >> 3) & 3, tt = c >> 5;
                const float4* src =
                    (const float4*)(out + ((size_t)(b0 + b) * S + (t + tt)) * H + h0);
                ((float4*)uB)[(tt * 4 + b) * 8 + rw4] = src[rw4];
            }
        }
        // ---- poll: sentinel wait (4/lane), then bulk + verify (r12) ----
        {
            const ull* src = pairs + ((size_t)((t & 1) * 8 + g)) * 4096;
            const unsigned tgt = (unsigned)t;
            ull v[16];
            for (;;) {
                ull s0 = __hip_atomic_load(src + 0 * 256 + tid, __ATOMIC_RELAXED,
                                           __HIP_MEMORY_SCOPE_AGENT);
                ull s1 = __hip_atomic_load(src + 5 * 256 + tid, __ATOMIC_RELAXED,
                                           __HIP_MEMORY_SCOPE_AGENT);
                ull s2 = __hip_atomic_load(src + 10 * 256 + tid, __ATOMIC_RELAXED,
                                           __HIP_MEMORY_SCOPE_AGENT);
                ull s3 = __hip_atomic_load(src + 15 * 256 + tid, __ATOMIC_RELAXED,
                                           __HIP_MEMORY_SCOPE_AGENT);
                int ok = ((unsigned)(s0 >> 32) == tgt) & ((unsigned)(s1 >> 32) == tgt)
                       & ((unsigned)(s2 >> 32) == tgt) & ((unsigned)(s3 >> 32) == tgt);
                if (__all(ok)) { v[0] = s0; v[5] = s1; v[10] = s2; v[15] = s3; break; }
            }
            for (;;) {
                int ok = 1;
#pragma unroll
                for (int c = 0; c < 16; ++c) {
                    if (c == 0 || c == 5 || c == 10 || c == 15) continue;
                    v[c] = __hip_atomic_load(src + c * 256 + tid, __ATOMIC_RELAXED,
                                             __HIP_MEMORY_SCOPE_AGENT);
                    ok &= ((unsigned)(v[c] >> 32) == tgt);
                }
                if (__all(ok)) break;
            }
            // convert to bf16 and store to Bb[b][h] (stride 1040: writes are
            // 2-lanes-per-dword pairs across all 32 banks = conflict-free)
#pragma unroll
            for (int c = 0; c < 16; ++c) {
                int n = c * 256 + tid;           // n = h*4 + b
                Bb[(n & 3) * 1040 + (n >> 2)] =
                    f32_to_bf16_rne(__uint_as_float((unsigned)v[c]));
            }
        }
        __syncthreads();

        // ---- compute: 16 MFMA per wave (2 M-tiles x 8 K-tiles) ----
        f4 c0 = (f4)(0.f), c1 = (f4)(0.f);
#pragma unroll
        for (int kt = 0; kt < 8; ++kt) {
            s8 bf = *(const s8*)(bbase + kt * 32);
            c0 = __builtin_amdgcn_mfma_f32_16x16x32_bf16(Afrag[kt],     bf, c0, 0, 0, 0);
            c1 = __builtin_amdgcn_mfma_f32_16x16x32_bf16(Afrag[8 + kt], bf, c1, 0, 0, 0);
        }
        // C/D: col=l&15, row=4*(l>>4)+j (m89). Only cols 0..3 are real.
        if (lc < 4) {
#pragma unroll
            for (int j = 0; j < 4; ++j) {
                red[(w * 32 + lg * 4 + j) * 4 + lc]      = c0[j];
                red[(w * 32 + 16 + lg * 4 + j) * 4 + lc] = c1[j];
            }
        }
        __syncthreads();

        // ---- finish (tid<128): publish tagged pair, FULL-LINE order ----
        if (tid < 128) {
            float sum = red[(0 * 32 + frw) * 4 + fb] + red[(1 * 32 + frw) * 4 + fb]
                      + red[(2 * 32 + frw) * 4 + fb] + red[(3 * 32 + frw) * 4 + fb];
            float uv = uL[((t >> 4) & 1) * 2048 + (((t & 15) * 4 + fb) << 5) + frw];
            float ns = LEAK * tanhf(uv + sum) + ILEAK * pv;
            pv = ns;
            ull pk = ((ull)(unsigned)(t + 1) << 32) | (ull)__float_as_uint(ns);
            __hip_atomic_store(
                pairs + ((size_t)(((t + 1) & 1) * 8 + g)) * 4096 + h0 * 4 + tid,
                pk, __ATOMIC_RELAXED, __HIP_MEMORY_SCOPE_AGENT);
            out[((size_t)(b0 + fb) * S + t) * H + h0 + frw] = ns;
        }
        __syncthreads();
    }
}

extern "C" void kernel_launch(void* const* d_in, const int* in_sizes, int n_in,
                              void* d_out, int out_size, void* d_ws, size_t ws_size,
                              hipStream_t stream)
{
    const float* x    = (const float*)d_in[0];   // [32][2048][512]
    const float* Win  = (const float*)d_in[1];   // [1024][512]
    const float* Wres = (const float*)d_in[2];   // [1024][1024]
    float* out = (float*)d_out;                  // [32][2048][1024]

    ull* pairs = (ull*)d_ws;                     // 2*8*4096*8 = 524288 B

    // zero pairs every launch: (tag 0, 0.0f) == step-0 initial state
    hipMemsetAsync(d_ws, 0, 524288, stream);

    // phase 1: u = x @ W_in^T into d_out
    dim3 gemm_grid(1024 / 64, 65536 / 64);
    resv_gemm_uin<<<gemm_grid, 256, 0, stream>>>(x, Win, out, 65536, 1024, 512);

    // phase 2: recurrence. 96KB dynamic LDS pins exactly 1 wg/CU
    // (co-residency of all 256 wgs proven rounds 1-15).
    constexpr int kLds = 96 * 1024;
    hipFuncSetAttribute((const void*)resv_recur,
                        hipFuncAttributeMaxDynamicSharedMemorySize, kLds);
    resv_recur<<<dim3(256), dim3(256), kLds, stream>>>(Wres, out, pairs);
}